// Round 6
// baseline (240.068 us; speedup 1.0000x reference)
//
#include <hip/hip_runtime.h>
#include <math.h>

#define T_N 2097152
#define NBM 1024               // blocks = 256 CUs * 4 blocks/CU (EXACT co-residency)
#define NT 256
#define EPT 8
#define CHUNK (NT * EPT)       // 2048 elements per block
#define GPT (NBM / NT)         // 4 block-summaries per thread in carry/final phases
#define GAMMA_F 0.99f
#define GL_F (0.99f * 0.95f)
#define LOG2PI_F 1.8378770664093453f

// ws layout (every slot rewritten each launch -> poison-safe):
//   ws +     0 : int ctrA, int ctrB     (memset to 0 at launch)
//   ws +     8 : u64 flag               (memset to 0 at launch)
//   ws +    16 : u64 stats[2]           ((mean_a,inv_a),(mean_r,inv_r)) - written before flag
//   ws +   256 : float4 blk[NBM*4]      extended block summaries
//   ws + 65792 : float2 car[NBM]        per-block entering carries (ret, adv)
//   ws + 73984 : float2 lblk[NBM]       per-block loss partials (actor, critic)
//
// Cross-block visibility: agent-scope relaxed atomics (sc1 -> coherence point),
// NO __threadfence() (r3 lesson: agent fence = per-block L2 wb-inv = 2x slowdown).
// Release ordering: sc1 stores -> per-wave vmcnt(0) drain (explicit or via
// __syncthreads) -> flag/ticket. Proven in r4/r5.
// Deadlock-freedom of the spin: grid 1024 == capacity (4 blocks/CU via
// __launch_bounds__(256,4) => VGPR<=128; LDS 25KB => 6/CU) -> all blocks resident.

__device__ __forceinline__ void st_agent(unsigned long long* p, unsigned long long v) {
    __hip_atomic_store(p, v, __ATOMIC_RELAXED, __HIP_MEMORY_SCOPE_AGENT);
}
__device__ __forceinline__ unsigned long long ld_agent(const unsigned long long* p) {
    return __hip_atomic_load(p, __ATOMIC_RELAXED, __HIP_MEMORY_SCOPE_AGENT);
}
__device__ __forceinline__ unsigned long long pk2(float x, float y) {
    union { float2 f; unsigned long long u; } c; c.f = make_float2(x, y); return c.u;
}
__device__ __forceinline__ float2 up2(unsigned long long v) {
    union { float2 f; unsigned long long u; } c; c.u = v; return c.f;
}

// ---------------- affine (A,B) pair for both recurrences ----------------
struct Aff4 { float ar, br, aa, ba; };
__device__ __forceinline__ Aff4 aff_id() { Aff4 o; o.ar = 1.f; o.br = 0.f; o.aa = 1.f; o.ba = 0.f; return o; }
__device__ __forceinline__ Aff4 aff_compose(const Aff4& L, const Aff4& R) {
    Aff4 o;
    o.ar = L.ar * R.ar;  o.br = fmaf(L.ar, R.br, L.br);
    o.aa = L.aa * R.aa;  o.ba = fmaf(L.aa, R.ba, L.ba);
    return o;
}
__device__ __forceinline__ Aff4 aff_shfl_down(const Aff4& x, int s) {
    Aff4 o;
    o.ar = __shfl_down(x.ar, s, 64); o.br = __shfl_down(x.br, s, 64);
    o.aa = __shfl_down(x.aa, s, 64); o.ba = __shfl_down(x.ba, s, 64);
    return o;
}
__device__ __forceinline__ Aff4 aff_wave_suffix(Aff4 x, int lane) {
#pragma unroll
    for (int s = 1; s < 64; s <<= 1) {
        Aff4 o = aff_shfl_down(x, s);
        if (lane + s < 64) x = aff_compose(x, o);
    }
    return x;
}

// ------------- extended segment: y-map + running sum + running sum-of-squares -------------
struct SegF { float A, B, P, S, U, V, Q; };
struct Seg2F { SegF r, a; };

__device__ __forceinline__ SegF segf_compose(const SegF& L, const SegF& R) {
    SegF o;
    o.A = L.A * R.A;
    o.B = fmaf(L.A, R.B, L.B);
    o.P = fmaf(L.P, R.A, R.P);
    o.S = fmaf(L.P, R.B, R.S) + L.S;
    float A2 = R.A * R.A, AB = R.A * R.B, B2 = R.B * R.B;
    o.U = fmaf(L.U, A2, R.U);
    o.V = fmaf(L.U, AB, fmaf(L.V, R.A, R.V));
    o.Q = fmaf(L.U, B2, fmaf(2.f * L.V, R.B, R.Q)) + L.Q;
    return o;
}
__device__ __forceinline__ Seg2F seg2f_compose(const Seg2F& L, const Seg2F& R) {
    Seg2F o; o.r = segf_compose(L.r, R.r); o.a = segf_compose(L.a, R.a); return o;
}
__device__ __forceinline__ SegF segf_shfl_down(const SegF& x, int s) {
    SegF o;
    o.A = __shfl_down(x.A, s, 64); o.B = __shfl_down(x.B, s, 64);
    o.P = __shfl_down(x.P, s, 64); o.S = __shfl_down(x.S, s, 64);
    o.U = __shfl_down(x.U, s, 64); o.V = __shfl_down(x.V, s, 64);
    o.Q = __shfl_down(x.Q, s, 64);
    return o;
}
__device__ __forceinline__ Seg2F seg2f_shfl_down(const Seg2F& x, int s) {
    Seg2F o; o.r = segf_shfl_down(x.r, s); o.a = segf_shfl_down(x.a, s); return o;
}
__device__ __forceinline__ Seg2F seg2f_id() {
    Seg2F o;
    o.r.A = 1.f; o.r.B = 0.f; o.r.P = 0.f; o.r.S = 0.f; o.r.U = 0.f; o.r.V = 0.f; o.r.Q = 0.f;
    o.a = o.r;
    return o;
}

__device__ __forceinline__ void load8(const float* __restrict__ rew,
                                      const float* __restrict__ val,
                                      const int* __restrict__ msk, int g,
                                      float rr[EPT], float vv[EPT], float mm[EPT],
                                      float& vnext) {
    float4 r0 = *(const float4*)(rew + g);
    float4 r1 = *(const float4*)(rew + g + 4);
    float4 v0 = *(const float4*)(val + g);
    float4 v1 = *(const float4*)(val + g + 4);
    int4 m0 = *(const int4*)(msk + g);
    int4 m1 = *(const int4*)(msk + g + 4);
    vnext = (g + EPT < T_N) ? val[g + EPT] : 0.f;
    rr[0]=r0.x; rr[1]=r0.y; rr[2]=r0.z; rr[3]=r0.w; rr[4]=r1.x; rr[5]=r1.y; rr[6]=r1.z; rr[7]=r1.w;
    vv[0]=v0.x; vv[1]=v0.y; vv[2]=v0.z; vv[3]=v0.w; vv[4]=v1.x; vv[5]=v1.y; vv[6]=v1.z; vv[7]=v1.w;
    mm[0]=(float)m0.x; mm[1]=(float)m0.y; mm[2]=(float)m0.z; mm[3]=(float)m0.w;
    mm[4]=(float)m1.x; mm[5]=(float)m1.y; mm[6]=(float)m1.z; mm[7]=(float)m1.w;
}

// blk record layout (8x8B): [0]=(rA,rB) [1]=(aA,aB) [2]=(rP,rS) [3]=(rU,rV)
//                           [4]=(rQ,aP) [5]=(aS,aU) [6]=(aV,aQ) [7]=pad
__device__ __forceinline__ Seg2F load_seg_agent(const float4* __restrict__ blk, int idx) {
    const unsigned long long* bp = (const unsigned long long*)(blk + (size_t)idx * 4);
    float2 a0 = up2(ld_agent(bp + 0));
    float2 a1 = up2(ld_agent(bp + 1));
    float2 a2 = up2(ld_agent(bp + 2));
    float2 a3 = up2(ld_agent(bp + 3));
    float2 a4 = up2(ld_agent(bp + 4));
    float2 a5 = up2(ld_agent(bp + 5));
    float2 a6 = up2(ld_agent(bp + 6));
    Seg2F s;
    s.r.A = a0.x; s.r.B = a0.y; s.a.A = a1.x; s.a.B = a1.y;
    s.r.P = a2.x; s.r.S = a2.y; s.r.U = a3.x; s.r.V = a3.y;
    s.r.Q = a4.x; s.a.P = a4.y; s.a.S = a5.x; s.a.U = a5.y;
    s.a.V = a6.x; s.a.Q = a6.y;
    return s;
}
__device__ __forceinline__ Aff4 load_aff_agent(const float4* __restrict__ blk, int idx) {
    const unsigned long long* bp = (const unsigned long long*)(blk + (size_t)idx * 4);
    float2 a0 = up2(ld_agent(bp + 0));
    float2 a1 = up2(ld_agent(bp + 1));
    Aff4 o; o.ar = a0.x; o.br = a0.y; o.aa = a1.x; o.ba = a1.y;
    return o;
}

// loss math for one float4 row
__device__ __forceinline__ void loss_row(float4 a, float4 m, float4 l, float4 bb,
                                         float AD, float RT, float VL,
                                         float mean_a, float inv_a, float mean_r, float inv_r,
                                         float& aacc, float& cacc) {
    float x0 = -0.5f * (a.x - m.x) * (a.x - m.x) * expf(-l.x) - 0.5f * l.x;
    float x1 = -0.5f * (a.y - m.y) * (a.y - m.y) * expf(-l.y) - 0.5f * l.y;
    float x2 = -0.5f * (a.z - m.z) * (a.z - m.z) * expf(-l.z) - 0.5f * l.z;
    float x3 = -0.5f * (a.w - m.w) * (a.w - m.w) * expf(-l.w) - 0.5f * l.w;
    float X = (x0 + x1 + x2 + x3) - (bb.x + bb.y + bb.z + bb.w) - 2.f * LOG2PI_F;
    float ratio = expf(X);
    float rc = fminf(fmaxf(ratio, 0.8f), 1.2f);
    float an = (AD - mean_a) * inv_a;
    aacc += fminf(ratio * an, rc * an);
    float rn = (RT - mean_r) * inv_r;
    float d = VL - rn;
    float adx = fabsf(d);
    cacc += (adx < 1.f) ? 0.5f * d * d : adx - 0.5f;
}

// ============ single fused kernel (no cooperative launch, no threadfence) ============
__global__ __launch_bounds__(NT, 4) void k_fused(const float* __restrict__ rew,
                                                 const float* __restrict__ val,
                                                 const int* __restrict__ msk,
                                                 const float4* __restrict__ act,
                                                 const float4* __restrict__ mu,
                                                 const float4* __restrict__ lv,
                                                 const float4* __restrict__ blp,
                                                 float4* __restrict__ blk,
                                                 float2* __restrict__ car,
                                                 unsigned long long* __restrict__ stats,
                                                 unsigned long long* __restrict__ flag,
                                                 float2* __restrict__ lblk,
                                                 int* __restrict__ ctrA,
                                                 int* __restrict__ ctrB,
                                                 float* __restrict__ out) {
    __shared__ Seg2F sW[4];
    __shared__ Aff4 sAw[4];
    __shared__ int sDone;
    __shared__ float sBc[6];
    __shared__ float sAdv[CHUNK], sRet[CHUNK], sVal[CHUNK];
    __shared__ float2 sL[4];
    __shared__ double sD[4][2];

    int tid = threadIdx.x, lane = tid & 63, wv = tid >> 6;
    int b = blockIdx.x;
    int gbase = b * CHUNK;
    int g = gbase + tid * EPT;

    // ---- hoisted loss rows 0..1 (lane-dense): latency hides under phase 1 + spin ----
    float4 A0[2], M0[2], L0[2], B0[2];
#pragma unroll
    for (int k = 0; k < 2; ++k) {
        int t = gbase + tid + k * NT;
        A0[k] = act[t]; M0[k] = mu[t]; L0[k] = lv[t]; B0[k] = blp[t];
    }

    // ---- phase 1: scan inputs (stay in registers for the WHOLE kernel) ----
    float rr[EPT], vv[EPT], mm[EPT], vnext;
    load8(rew, val, msk, g, rr, vv, mm, vnext);

    Seg2F x = seg2f_id();
    {
        float vn = vnext;
#pragma unroll
        for (int j = EPT - 1; j >= 0; --j) {
            float m = mm[j];
            float ar = GAMMA_F * m, br = rr[j];
            float aa = GL_F * m;
            float delta = fmaf(GAMMA_F * vn, m, rr[j]) - vv[j];
            Seg2F e;
            e.r.A = ar; e.r.B = br; e.r.P = ar; e.r.S = br; e.r.U = ar * ar; e.r.V = ar * br; e.r.Q = br * br;
            e.a.A = aa; e.a.B = delta; e.a.P = aa; e.a.S = delta; e.a.U = aa * aa; e.a.V = aa * delta; e.a.Q = delta * delta;
            x = seg2f_compose(e, x);
            vn = vv[j];
        }
    }
    // guarded wave suffix scan: lane l -> compose(x_l..x_63); also yields per-lane exclusive
    Seg2F incl = x;
#pragma unroll
    for (int s = 1; s < 64; s <<= 1) {
        Seg2F o = seg2f_shfl_down(incl, s);
        if (lane + s < 64) incl = seg2f_compose(incl, o);
    }
    Seg2F ex = seg2f_shfl_down(incl, 1);
    if (lane == 63) ex = seg2f_id();
    if (lane == 0) sW[wv] = incl;
    __syncthreads();
    Seg2F tail = seg2f_id();
    for (int w = 3; w > wv; --w) tail = seg2f_compose(sW[w], tail);
    // per-thread exclusive affine prefix within block (affine fields compose independently,
    // bitwise identical to aff_compose(ex_aff, tail_aff))
    float exrA = ex.r.A * tail.r.A;
    float exrB = fmaf(ex.r.A, tail.r.B, ex.r.B);
    float exaA = ex.a.A * tail.a.A;
    float exaB = fmaf(ex.a.A, tail.a.B, ex.a.B);

    if (tid == 0) {
        Seg2F t = seg2f_compose(incl, tail);   // block total (incl@lane0 of wave 0)
        unsigned long long* bp = (unsigned long long*)(blk + (size_t)b * 4);
        st_agent(bp + 0, pk2(t.r.A, t.r.B));
        st_agent(bp + 1, pk2(t.a.A, t.a.B));
        st_agent(bp + 2, pk2(t.r.P, t.r.S));
        st_agent(bp + 3, pk2(t.r.U, t.r.V));
        st_agent(bp + 4, pk2(t.r.Q, t.a.P));
        st_agent(bp + 5, pk2(t.a.S, t.a.U));
        st_agent(bp + 6, pk2(t.a.V, t.a.Q));
        st_agent(bp + 7, 0ULL);
        asm volatile("s_waitcnt vmcnt(0)" ::: "memory");   // release: stores at coherence point
        sDone = atomicAdd(ctrA, 1);
    }
    __syncthreads();

    if (sDone == NBM - 1) {
        // ---- LAST block: carry scan over NBM summaries + global stats (r5-verified tail) ----
        Seg2F gcS = seg2f_id();
#pragma unroll 1
        for (int p = GPT - 1; p >= 0; --p)
            gcS = seg2f_compose(load_seg_agent(blk, tid * GPT + p), gcS);
        Aff4 gA; gA.ar = gcS.r.A; gA.br = gcS.r.B; gA.aa = gcS.a.A; gA.ba = gcS.a.B;
        // stats: ordered wave down-reduction (lane-0 valid)
        Seg2F red = gcS;
#pragma unroll
        for (int s = 1; s < 64; s <<= 1) {
            Seg2F o = seg2f_shfl_down(red, s);
            red = seg2f_compose(red, o);
        }
        if (lane == 0) sW[wv] = red;           // safe: phase-1 sW reads done before last barrier
        // affine suffix scan for the carries
        Aff4 inclA = aff_wave_suffix(gA, lane);
        Aff4 exA = aff_shfl_down(inclA, 1);
        if (lane == 63) exA = aff_id();
        if (lane == 0) sAw[wv] = inclA;
        __syncthreads();
        Aff4 tailA = aff_id();
        for (int w = 3; w > wv; --w) tailA = aff_compose(sAw[w], tailA);
        Aff4 H = aff_compose(exA, tailA);      // composition of all summaries after this group
#pragma unroll 1
        for (int p = GPT - 1; p >= 0; --p) {
            st_agent((unsigned long long*)(car + tid * GPT + p), pk2(H.br, H.ba));
            if (p) H = aff_compose(load_aff_agent(blk, tid * GPT + p), H);
        }
        __syncthreads();                       // drains every wave's vmcnt -> all car stores released
        if (tid == 0) {
            Seg2F tot = sW[3];
            tot = seg2f_compose(sW[2], tot);
            tot = seg2f_compose(sW[1], tot);
            tot = seg2f_compose(sW[0], tot);   // full composition; y_in = 0
            const double Td = (double)T_N;
            double Sa = (double)tot.a.S, Qa = (double)tot.a.Q;
            double Sr = (double)tot.r.S, Qr = (double)tot.r.Q;
            double va = (Qa - Sa * Sa / Td) / (Td - 1.0);
            double vr = (Qr - Sr * Sr / Td) / (Td - 1.0);
            st_agent(stats + 0, pk2((float)(Sa / Td), (float)(1.0 / (sqrt(va) + 1e-10))));
            st_agent(stats + 1, pk2((float)(Sr / Td), (float)(1.0 / (sqrt(vr) + 1e-10))));
            asm volatile("s_waitcnt vmcnt(0)" ::: "memory");
            st_agent(flag, 1ULL);              // publish: car + stats now visible
        }
    }

    // ---- spin until stats/car published (deadlock-free: all 1024 blocks resident) ----
    if (tid == 0) {
        while (ld_agent(flag) == 0ULL) __builtin_amdgcn_s_sleep(8);
        float2 s0 = up2(ld_agent(stats + 0));
        float2 s1 = up2(ld_agent(stats + 1));
        float2 cb = up2(ld_agent((const unsigned long long*)(car + b)));
        sBc[0] = s0.x; sBc[1] = s0.y; sBc[2] = s1.x; sBc[3] = s1.y; sBc[4] = cb.x; sBc[5] = cb.y;
    }
    __syncthreads();
    float mean_a = sBc[0], inv_a = sBc[1], mean_r = sBc[2], inv_r = sBc[3];
    float2 c = make_float2(sBc[4], sBc[5]);

    // ---- loss rows 2..3 issued before the dependent walk ----
    float4 A1[2], M1[2], L1[2], B1[2];
#pragma unroll
    for (int k = 0; k < 2; ++k) {
        int t = gbase + tid + (k + 2) * NT;
        A1[k] = act[t]; M1[k] = mu[t]; L1[k] = lv[t]; B1[k] = blp[t];
    }

    // ---- phase 3: ret/adv walk (inputs still in registers) ----
    float yr = fmaf(exrA, c.x, exrB);
    float ya = fmaf(exaA, c.y, exaB);
    float retj[EPT], advj[EPT];
    float vn = vnext;
#pragma unroll
    for (int j = EPT - 1; j >= 0; --j) {
        float m = mm[j];
        float gm = GAMMA_F * m;
        yr = fmaf(gm, yr, rr[j]);  retj[j] = yr;
        float delta = fmaf(GAMMA_F * vn, m, rr[j]) - vv[j];
        ya = fmaf(GL_F * m, ya, delta);  advj[j] = ya;
        vn = vv[j];
    }
    // ---- LDS bridge: scan layout -> lane-dense ----
    *(float4*)(sAdv + tid * EPT)     = make_float4(advj[0], advj[1], advj[2], advj[3]);
    *(float4*)(sAdv + tid * EPT + 4) = make_float4(advj[4], advj[5], advj[6], advj[7]);
    *(float4*)(sRet + tid * EPT)     = make_float4(retj[0], retj[1], retj[2], retj[3]);
    *(float4*)(sRet + tid * EPT + 4) = make_float4(retj[4], retj[5], retj[6], retj[7]);
    *(float4*)(sVal + tid * EPT)     = make_float4(vv[0], vv[1], vv[2], vv[3]);
    *(float4*)(sVal + tid * EPT + 4) = make_float4(vv[4], vv[5], vv[6], vv[7]);
    __syncthreads();

    // ---- loss rows 4..7 issued before consuming rows 0..3 ----
    float4 A2[4], M2[4], L2[4], B2[4];
#pragma unroll
    for (int k = 0; k < 4; ++k) {
        int t = gbase + tid + (k + 4) * NT;
        A2[k] = act[t]; M2[k] = mu[t]; L2[k] = lv[t]; B2[k] = blp[t];
    }

    float aacc = 0.f, cacc = 0.f;
#pragma unroll
    for (int k = 0; k < 2; ++k) {
        int r = tid + k * NT;
        loss_row(A0[k], M0[k], L0[k], B0[k], sAdv[r], sRet[r], sVal[r],
                 mean_a, inv_a, mean_r, inv_r, aacc, cacc);
    }
#pragma unroll
    for (int k = 0; k < 2; ++k) {
        int r = tid + (k + 2) * NT;
        loss_row(A1[k], M1[k], L1[k], B1[k], sAdv[r], sRet[r], sVal[r],
                 mean_a, inv_a, mean_r, inv_r, aacc, cacc);
    }
#pragma unroll
    for (int k = 0; k < 4; ++k) {
        int r = tid + (k + 4) * NT;
        loss_row(A2[k], M2[k], L2[k], B2[k], sAdv[r], sRet[r], sVal[r],
                 mean_a, inv_a, mean_r, inv_r, aacc, cacc);
    }
#pragma unroll
    for (int s = 32; s > 0; s >>= 1) {
        aacc += __shfl_xor(aacc, s, 64);
        cacc += __shfl_xor(cacc, s, 64);
    }
    if (lane == 0) sL[wv] = make_float2(aacc, cacc);
    __syncthreads();
    if (tid == 0) {
        st_agent((unsigned long long*)(lblk + b),
                 pk2(sL[0].x + sL[1].x + sL[2].x + sL[3].x,
                     sL[0].y + sL[1].y + sL[2].y + sL[3].y));
        asm volatile("s_waitcnt vmcnt(0)" ::: "memory");
        sDone = atomicAdd(ctrB, 1);
    }
    __syncthreads();
    if (sDone != NBM - 1) return;

    // ---- last-to-finish block: final reduce in double ----
    double ac = 0, cr = 0;
#pragma unroll
    for (int p = 0; p < GPT; ++p) {
        float2 v2 = up2(ld_agent((const unsigned long long*)(lblk + tid + p * NT)));
        ac += v2.x; cr += v2.y;
    }
#pragma unroll
    for (int s = 32; s > 0; s >>= 1) {
        ac += __shfl_xor(ac, s, 64);
        cr += __shfl_xor(cr, s, 64);
    }
    if (lane == 0) { sD[wv][0] = ac; sD[wv][1] = cr; }
    __syncthreads();
    if (tid == 0) {
        ac = sD[0][0] + sD[1][0] + sD[2][0] + sD[3][0];
        cr = sD[0][1] + sD[1][1] + sD[2][1] + sD[3][1];
        out[0] = (float)((-ac + cr) / (double)T_N);
    }
}

extern "C" void kernel_launch(void* const* d_in, const int* in_sizes, int n_in,
                              void* d_out, int out_size, void* d_ws, size_t ws_size,
                              hipStream_t stream) {
    const float* rew = (const float*)d_in[0];
    const float* val = (const float*)d_in[1];
    const float4* blp = (const float4*)d_in[2];
    const float4* act = (const float4*)d_in[3];
    const float4* mu  = (const float4*)d_in[4];
    const float4* lv  = (const float4*)d_in[5];
    const int*   msk = (const int*)d_in[6];

    char* ws = (char*)d_ws;
    int* ctrA = (int*)ws;                                       // 0..3
    int* ctrB = (int*)(ws + 4);                                 // 4..7
    unsigned long long* flag  = (unsigned long long*)(ws + 8);  // 8..15
    unsigned long long* stats = (unsigned long long*)(ws + 16); // 16..31
    float4* blk  = (float4*)(ws + 256);                         // NBM*64 = 65536 B
    float2* car  = (float2*)(ws + 256 + NBM * 64);              // NBM*8  =  8192 B
    float2* lblk = (float2*)(ws + 256 + NBM * 72);              // NBM*8  =  8192 B

    hipMemsetAsync(ws, 0, 16, stream);   // reset ctrA, ctrB, flag (capturable)
    k_fused<<<NBM, NT, 0, stream>>>(rew, val, msk, act, mu, lv, blp,
                                    blk, car, stats, flag, lblk, ctrA, ctrB, (float*)d_out);
}

// Round 8
// 196.637 us; speedup vs baseline: 1.2209x; 1.2209x over previous
//
#include <hip/hip_runtime.h>
#include <math.h>

#define T_N 2097152
#define NBM 1024               // blocks (4 per CU on 256 CUs)
#define NT 256
#define EPT 8
#define CHUNK (NT * EPT)       // 2048 elements per block
#define GPT (NBM / NT)         // 4 block-summaries per thread in carry/final phases
#define GAMMA_F 0.99f
#define GL_F (0.99f * 0.95f)
#define LOG2PI_F 1.8378770664093453f

// ws layout (every slot rewritten each launch -> poison-safe):
//   ws +     0 : int ctrA, int ctrB      (memset to 0 at launch)
//   ws +    16 : float stats[4]          (mean_a, inv_a, mean_r, inv_r)
//   ws +   256 : float4 blk[NBM*4]       extended block summaries (14 floats padded to 16)
//   ws + 65792 : float2 car[NBM]         per-block entering carries (ret, adv)
//   ws + 73984 : float2 lblk[NBM]        per-block loss partials (actor, critic)
//
// Cross-block visibility WITHIN a kernel: agent-scope relaxed atomics (sc1 ->
// coherence point). NO __threadfence() (r3: agent fence = per-block L2
// writeback-invalidate = 2x slowdown). NO spin-waits (r6: grid-wide spin +
// register state held across it = spills + serialization). Last-ticket blocks
// do tail work; cross-KERNEL visibility rides the dispatch boundary (r4-proven).

__device__ __forceinline__ void st_agent(unsigned long long* p, unsigned long long v) {
    __hip_atomic_store(p, v, __ATOMIC_RELAXED, __HIP_MEMORY_SCOPE_AGENT);
}
__device__ __forceinline__ unsigned long long ld_agent(const unsigned long long* p) {
    return __hip_atomic_load(p, __ATOMIC_RELAXED, __HIP_MEMORY_SCOPE_AGENT);
}
__device__ __forceinline__ unsigned long long pk2(float x, float y) {
    union { float2 f; unsigned long long u; } c; c.f = make_float2(x, y); return c.u;
}
__device__ __forceinline__ float2 up2(unsigned long long v) {
    union { float2 f; unsigned long long u; } c; c.u = v; return c.f;
}

// ---------------- affine (A,B) pair for both recurrences ----------------
struct Aff4 { float ar, br, aa, ba; };
__device__ __forceinline__ Aff4 aff_id() { Aff4 o; o.ar = 1.f; o.br = 0.f; o.aa = 1.f; o.ba = 0.f; return o; }
// L earlier in time (applied second in reverse scan): (L o R)(y) = L(R(y))
__device__ __forceinline__ Aff4 aff_compose(const Aff4& L, const Aff4& R) {
    Aff4 o;
    o.ar = L.ar * R.ar;  o.br = fmaf(L.ar, R.br, L.br);
    o.aa = L.aa * R.aa;  o.ba = fmaf(L.aa, R.ba, L.ba);
    return o;
}
__device__ __forceinline__ Aff4 aff_shfl_down(const Aff4& x, int s) {
    Aff4 o;
    o.ar = __shfl_down(x.ar, s, 64); o.br = __shfl_down(x.br, s, 64);
    o.aa = __shfl_down(x.aa, s, 64); o.ba = __shfl_down(x.ba, s, 64);
    return o;
}
__device__ __forceinline__ Aff4 aff_wave_suffix(Aff4 x, int lane) {
#pragma unroll
    for (int s = 1; s < 64; s <<= 1) {
        Aff4 o = aff_shfl_down(x, s);
        if (lane + s < 64) x = aff_compose(x, o);
    }
    return x;
}

// ------------- extended segment: y-map + running sum + running sum-of-squares -------------
// y_out = A*y + B ; Sum(y_t) = P*y + S ; Sum(y_t^2) = U*y^2 + 2*V*y + Q   (y = incoming state)
struct SegF { float A, B, P, S, U, V, Q; };
struct Seg2F { SegF r, a; };

__device__ __forceinline__ SegF segf_compose(const SegF& L, const SegF& R) {
    SegF o;
    o.A = L.A * R.A;
    o.B = fmaf(L.A, R.B, L.B);
    o.P = fmaf(L.P, R.A, R.P);
    o.S = fmaf(L.P, R.B, R.S) + L.S;
    float A2 = R.A * R.A, AB = R.A * R.B, B2 = R.B * R.B;
    o.U = fmaf(L.U, A2, R.U);
    o.V = fmaf(L.U, AB, fmaf(L.V, R.A, R.V));
    o.Q = fmaf(L.U, B2, fmaf(2.f * L.V, R.B, R.Q)) + L.Q;
    return o;
}
__device__ __forceinline__ Seg2F seg2f_compose(const Seg2F& L, const Seg2F& R) {
    Seg2F o; o.r = segf_compose(L.r, R.r); o.a = segf_compose(L.a, R.a); return o;
}
__device__ __forceinline__ SegF segf_shfl_down(const SegF& x, int s) {
    SegF o;
    o.A = __shfl_down(x.A, s, 64); o.B = __shfl_down(x.B, s, 64);
    o.P = __shfl_down(x.P, s, 64); o.S = __shfl_down(x.S, s, 64);
    o.U = __shfl_down(x.U, s, 64); o.V = __shfl_down(x.V, s, 64);
    o.Q = __shfl_down(x.Q, s, 64);
    return o;
}
__device__ __forceinline__ Seg2F seg2f_shfl_down(const Seg2F& x, int s) {
    Seg2F o; o.r = segf_shfl_down(x.r, s); o.a = segf_shfl_down(x.a, s); return o;
}
__device__ __forceinline__ Seg2F seg2f_id() {
    Seg2F o;
    o.r.A = 1.f; o.r.B = 0.f; o.r.P = 0.f; o.r.S = 0.f; o.r.U = 0.f; o.r.V = 0.f; o.r.Q = 0.f;
    o.a = o.r;
    return o;
}

// Affine-only thread transform over EPT contiguous elements (right-to-left).
__device__ __forceinline__ Aff4 thread_transform(const float rr[EPT], const float vv[EPT],
                                                 const float mm[EPT], float vnext) {
    Aff4 x = aff_id();
    float vn = vnext;
#pragma unroll
    for (int j = EPT - 1; j >= 0; --j) {
        float m = mm[j];
        float gm = GAMMA_F * m;
        x.br = fmaf(gm, x.br, rr[j]);  x.ar = gm * x.ar;              // ret: y = gm*y + r
        float delta = fmaf(GAMMA_F * vn, m, rr[j]) - vv[j];
        float gl = GL_F * m;
        x.ba = fmaf(gl, x.ba, delta);  x.aa = gl * x.aa;              // adv: y = gl*y + delta
        vn = vv[j];
    }
    return x;
}

__device__ __forceinline__ void load8(const float* __restrict__ rew,
                                      const float* __restrict__ val,
                                      const int* __restrict__ msk, int g,
                                      float rr[EPT], float vv[EPT], float mm[EPT],
                                      float& vnext) {
    float4 r0 = *(const float4*)(rew + g);
    float4 r1 = *(const float4*)(rew + g + 4);
    float4 v0 = *(const float4*)(val + g);
    float4 v1 = *(const float4*)(val + g + 4);
    int4 m0 = *(const int4*)(msk + g);
    int4 m1 = *(const int4*)(msk + g + 4);
    vnext = (g + EPT < T_N) ? val[g + EPT] : 0.f;
    rr[0]=r0.x; rr[1]=r0.y; rr[2]=r0.z; rr[3]=r0.w; rr[4]=r1.x; rr[5]=r1.y; rr[6]=r1.z; rr[7]=r1.w;
    vv[0]=v0.x; vv[1]=v0.y; vv[2]=v0.z; vv[3]=v0.w; vv[4]=v1.x; vv[5]=v1.y; vv[6]=v1.z; vv[7]=v1.w;
    mm[0]=(float)m0.x; mm[1]=(float)m0.y; mm[2]=(float)m0.z; mm[3]=(float)m0.w;
    mm[4]=(float)m1.x; mm[5]=(float)m1.y; mm[6]=(float)m1.z; mm[7]=(float)m1.w;
}

// blk record layout (8x8B): [0]=(rA,rB) [1]=(aA,aB) [2]=(rP,rS) [3]=(rU,rV)
//                           [4]=(rQ,aP) [5]=(aS,aU) [6]=(aV,aQ) [7]=pad
__device__ __forceinline__ Seg2F load_seg_agent(const float4* __restrict__ blk, int idx) {
    const unsigned long long* bp = (const unsigned long long*)(blk + (size_t)idx * 4);
    float2 a0 = up2(ld_agent(bp + 0));
    float2 a1 = up2(ld_agent(bp + 1));
    float2 a2 = up2(ld_agent(bp + 2));
    float2 a3 = up2(ld_agent(bp + 3));
    float2 a4 = up2(ld_agent(bp + 4));
    float2 a5 = up2(ld_agent(bp + 5));
    float2 a6 = up2(ld_agent(bp + 6));
    Seg2F s;
    s.r.A = a0.x; s.r.B = a0.y; s.a.A = a1.x; s.a.B = a1.y;
    s.r.P = a2.x; s.r.S = a2.y; s.r.U = a3.x; s.r.V = a3.y;
    s.r.Q = a4.x; s.a.P = a4.y; s.a.S = a5.x; s.a.U = a5.y;
    s.a.V = a6.x; s.a.Q = a6.y;
    return s;
}

// loss math for one float4 row
__device__ __forceinline__ void loss_row(float4 a, float4 m, float4 l, float4 bb,
                                         float AD, float RT, float VL,
                                         float mean_a, float inv_a, float mean_r, float inv_r,
                                         float& aacc, float& cacc) {
    float x0 = -0.5f * (a.x - m.x) * (a.x - m.x) * expf(-l.x) - 0.5f * l.x;
    float x1 = -0.5f * (a.y - m.y) * (a.y - m.y) * expf(-l.y) - 0.5f * l.y;
    float x2 = -0.5f * (a.z - m.z) * (a.z - m.z) * expf(-l.z) - 0.5f * l.z;
    float x3 = -0.5f * (a.w - m.w) * (a.w - m.w) * expf(-l.w) - 0.5f * l.w;
    float X = (x0 + x1 + x2 + x3) - (bb.x + bb.y + bb.z + bb.w) - 2.f * LOG2PI_F;
    float ratio = expf(X);
    float rc = fminf(fmaxf(ratio, 0.8f), 1.2f);
    float an = (AD - mean_a) * inv_a;
    aacc += fminf(ratio * an, rc * an);
    float rn = (RT - mean_r) * inv_r;
    float d = VL - rn;
    float adx = fabsf(d);
    cacc += (adx < 1.f) ? 0.5f * d * d : adx - 0.5f;
}

// ============ K1: extended block summaries; LAST block also does carry scan + stats ============
__global__ __launch_bounds__(NT) void k_summ(const float* __restrict__ rew,
                                             const float* __restrict__ val,
                                             const int* __restrict__ msk,
                                             float4* __restrict__ blk,
                                             float2* __restrict__ car,
                                             float* __restrict__ stats,
                                             int* __restrict__ ctr) {
    int tid = threadIdx.x, lane = tid & 63, wv = tid >> 6;
    int b = blockIdx.x;
    int g = b * CHUNK + tid * EPT;
    float rr[EPT], vv[EPT], mm[EPT], vnext;
    load8(rew, val, msk, g, rr, vv, mm, vnext);
    Seg2F x = seg2f_id();
    float vn = vnext;
#pragma unroll
    for (int j = EPT - 1; j >= 0; --j) {
        float m = mm[j];
        float ar = GAMMA_F * m, br = rr[j];
        float aa = GL_F * m;
        float delta = fmaf(GAMMA_F * vn, m, rr[j]) - vv[j];
        Seg2F e;
        e.r.A = ar; e.r.B = br; e.r.P = ar; e.r.S = br; e.r.U = ar * ar; e.r.V = ar * br; e.r.Q = br * br;
        e.a.A = aa; e.a.B = delta; e.a.P = aa; e.a.S = delta; e.a.U = aa * aa; e.a.V = aa * delta; e.a.Q = delta * delta;
        x = seg2f_compose(e, x);
        vn = vv[j];
    }
    // ordered down-reduction: lane 0 ends with composition of lanes [0,64)
#pragma unroll
    for (int s = 1; s < 64; s <<= 1) {
        Seg2F o = seg2f_shfl_down(x, s);
        x = seg2f_compose(x, o);
    }
    __shared__ Seg2F sW[4];
    __shared__ int sDone;
    if (lane == 0) sW[wv] = x;
    __syncthreads();
    if (tid == 0) {
        Seg2F t = sW[3];
        t = seg2f_compose(sW[2], t);
        t = seg2f_compose(sW[1], t);
        t = seg2f_compose(sW[0], t);
        unsigned long long* bp = (unsigned long long*)(blk + (size_t)b * 4);
        st_agent(bp + 0, pk2(t.r.A, t.r.B));
        st_agent(bp + 1, pk2(t.a.A, t.a.B));
        st_agent(bp + 2, pk2(t.r.P, t.r.S));
        st_agent(bp + 3, pk2(t.r.U, t.r.V));
        st_agent(bp + 4, pk2(t.r.Q, t.a.P));
        st_agent(bp + 5, pk2(t.a.S, t.a.U));
        st_agent(bp + 6, pk2(t.a.V, t.a.Q));
        st_agent(bp + 7, 0ULL);
        asm volatile("s_waitcnt vmcnt(0)" ::: "memory");   // release: stores at coherence point
        sDone = atomicAdd(ctr, 1);                          // device-coherent ticket
    }
    __syncthreads();
    if (sDone != NBM - 1) return;

    // ---- last block: carry scan over NBM summaries + global stats ----
    Seg2F s[GPT];
#pragma unroll
    for (int p = 0; p < GPT; ++p) s[p] = load_seg_agent(blk, tid * GPT + p);
    Seg2F gc = seg2f_id();
#pragma unroll
    for (int p = GPT - 1; p >= 0; --p) gc = seg2f_compose(s[p], gc);
    Seg2F incl = gc;
#pragma unroll
    for (int ss = 1; ss < 64; ss <<= 1) {
        Seg2F o = seg2f_shfl_down(incl, ss);
        if (lane + ss < 64) incl = seg2f_compose(incl, o);
    }
    Seg2F ex = seg2f_shfl_down(incl, 1);
    if (lane == 63) ex = seg2f_id();
    if (lane == 0) sW[wv] = incl;              // safe: phase-1 sW reads done before ticket sync
    __syncthreads();
    Seg2F tail = seg2f_id();
    for (int w = 3; w > wv; --w) tail = seg2f_compose(sW[w], tail);
    Seg2F H = seg2f_compose(ex, tail);         // composition of all summaries after this thread's group
#pragma unroll
    for (int p = GPT - 1; p >= 0; --p) {
        car[tid * GPT + p] = make_float2(H.r.B, H.a.B);   // carry entering block = H(0)
        H = seg2f_compose(s[p], H);
    }
    if (tid == 0) {
        Seg2F tot = seg2f_compose(incl, tail);   // full composition; y_in = 0
        const double Td = (double)T_N;
        double Sa = (double)tot.a.S, Qa = (double)tot.a.Q;
        double Sr = (double)tot.r.S, Qr = (double)tot.r.Q;
        double va = (Qa - Sa * Sa / Td) / (Td - 1.0);
        double vr = (Qr - Sr * Sr / Td) / (Td - 1.0);
        stats[0] = (float)(Sa / Td);
        stats[1] = (float)(1.0 / (sqrt(va) + 1e-10));
        stats[2] = (float)(Sr / Td);
        stats[3] = (float)(1.0 / (sqrt(vr) + 1e-10));
    }
    // car/stats visibility to k_main rides the kernel-boundary implicit flush
}

// ============ K2: FULL loss prefetch -> scan -> loss from registers ============
// All 32 loss float4s are issued BEFORE the scan so ~500B/thread of HBM latency
// hides under the scan's shuffle chain + LDS bridge. The asm memory clobbers pin
// the loads (a load may not sink across a potential memory write). No
// launch_bounds clamp: the allocator needs ~200 VGPR to keep the batch live
// (r0/r6 lesson: at VGPR<=128 the compiler sinks or spills the batch).
__global__ __launch_bounds__(NT) void k_main(const float* __restrict__ rew,
                                             const float* __restrict__ val,
                                             const int* __restrict__ msk,
                                             const float4* __restrict__ act,
                                             const float4* __restrict__ mu,
                                             const float4* __restrict__ lv,
                                             const float4* __restrict__ blp,
                                             const float2* __restrict__ car,
                                             const float* __restrict__ stats,
                                             float2* __restrict__ lblk,
                                             int* __restrict__ ctr,
                                             float* __restrict__ out) {
    int tid = threadIdx.x, lane = tid & 63, wv = tid >> 6;
    int b = blockIdx.x;
    int gbase = b * CHUNK;

    // ---- prefetch ALL loss rows (lane-dense coalesced), pinned early ----
    float4 A[8], M[8], L[8], B[8];
#pragma unroll
    for (int k = 0; k < 8; ++k) {
        int t = gbase + tid + k * NT;
        A[k] = act[t]; M[k] = mu[t]; L[k] = lv[t]; B[k] = blp[t];
    }
    asm volatile("" ::: "memory");   // loads may not sink below this point

    float mean_a = stats[0], inv_a = stats[1], mean_r = stats[2], inv_r = stats[3];
    float2 c = car[b];

    // ---- scan inputs + phase-1 scan (overlaps the in-flight prefetch) ----
    int g = gbase + tid * EPT;
    float rr[EPT], vv[EPT], mm[EPT], vnext;
    load8(rew, val, msk, g, rr, vv, mm, vnext);
    Aff4 x = thread_transform(rr, vv, mm, vnext);
    Aff4 incl = aff_wave_suffix(x, lane);
    Aff4 ex = aff_shfl_down(incl, 1);
    if (lane == 63) ex = aff_id();
    __shared__ Aff4 sA[4];
    if (lane == 0) sA[wv] = incl;
    __syncthreads();
    Aff4 tail = aff_id();
    for (int w = 3; w > wv; --w) tail = aff_compose(sA[w], tail);
    ex = aff_compose(ex, tail);
    float yr = fmaf(ex.ar, c.x, ex.br);
    float ya = fmaf(ex.aa, c.y, ex.ba);
    float retj[EPT], advj[EPT];
    float vn = vnext;
#pragma unroll
    for (int j = EPT - 1; j >= 0; --j) {
        float m = mm[j];
        float gm = GAMMA_F * m;
        yr = fmaf(gm, yr, rr[j]);  retj[j] = yr;
        float delta = fmaf(GAMMA_F * vn, m, rr[j]) - vv[j];
        ya = fmaf(GL_F * m, ya, delta);  advj[j] = ya;
        vn = vv[j];
    }
    // ---- LDS bridge: scan layout -> lane-dense ----
    __shared__ float sAdv[CHUNK], sRet[CHUNK], sVal[CHUNK];
    *(float4*)(sAdv + tid * EPT)     = make_float4(advj[0], advj[1], advj[2], advj[3]);
    *(float4*)(sAdv + tid * EPT + 4) = make_float4(advj[4], advj[5], advj[6], advj[7]);
    *(float4*)(sRet + tid * EPT)     = make_float4(retj[0], retj[1], retj[2], retj[3]);
    *(float4*)(sRet + tid * EPT + 4) = make_float4(retj[4], retj[5], retj[6], retj[7]);
    *(float4*)(sVal + tid * EPT)     = make_float4(vv[0], vv[1], vv[2], vv[3]);
    *(float4*)(sVal + tid * EPT + 4) = make_float4(vv[4], vv[5], vv[6], vv[7]);
    __syncthreads();

    // ---- loss: registers + LDS only (no new global loads) ----
    float aacc = 0.f, cacc = 0.f;
#pragma unroll
    for (int k = 0; k < 8; ++k) {
        int r = tid + k * NT;
        loss_row(A[k], M[k], L[k], B[k], sAdv[r], sRet[r], sVal[r],
                 mean_a, inv_a, mean_r, inv_r, aacc, cacc);
    }
#pragma unroll
    for (int s = 32; s > 0; s >>= 1) {
        aacc += __shfl_xor(aacc, s, 64);
        cacc += __shfl_xor(cacc, s, 64);
    }
    __shared__ float2 sL[4];
    __shared__ int sDone;
    if (lane == 0) sL[wv] = make_float2(aacc, cacc);
    __syncthreads();
    if (tid == 0) {
        st_agent((unsigned long long*)(lblk + b),
                 pk2(sL[0].x + sL[1].x + sL[2].x + sL[3].x,
                     sL[0].y + sL[1].y + sL[2].y + sL[3].y));
        asm volatile("s_waitcnt vmcnt(0)" ::: "memory");
        sDone = atomicAdd(ctr, 1);
    }
    __syncthreads();
    if (sDone != NBM - 1) return;

    // ---- last block: final reduce in double (sc1 reads) ----
    double ac = 0, cr = 0;
#pragma unroll
    for (int p = 0; p < NBM / NT; ++p) {
        float2 v2 = up2(ld_agent((const unsigned long long*)(lblk + tid + p * NT)));
        ac += v2.x; cr += v2.y;
    }
#pragma unroll
    for (int s = 32; s > 0; s >>= 1) {
        ac += __shfl_xor(ac, s, 64);
        cr += __shfl_xor(cr, s, 64);
    }
    __shared__ double sD[4][2];
    if (lane == 0) { sD[wv][0] = ac; sD[wv][1] = cr; }
    __syncthreads();
    if (tid == 0) {
        ac = sD[0][0] + sD[1][0] + sD[2][0] + sD[3][0];
        cr = sD[0][1] + sD[1][1] + sD[2][1] + sD[3][1];
        out[0] = (float)((-ac + cr) / (double)T_N);
    }
}

extern "C" void kernel_launch(void* const* d_in, const int* in_sizes, int n_in,
                              void* d_out, int out_size, void* d_ws, size_t ws_size,
                              hipStream_t stream) {
    const float* rew = (const float*)d_in[0];
    const float* val = (const float*)d_in[1];
    const float4* blp = (const float4*)d_in[2];
    const float4* act = (const float4*)d_in[3];
    const float4* mu  = (const float4*)d_in[4];
    const float4* lv  = (const float4*)d_in[5];
    const int*   msk = (const int*)d_in[6];

    char* ws = (char*)d_ws;
    int*    ctrA  = (int*)ws;                          // 4 B
    int*    ctrB  = (int*)(ws + 4);                    // 4 B
    float*  stats = (float*)(ws + 16);                 // 16 B
    float4* blk   = (float4*)(ws + 256);               // NBM*64 = 65536 B
    float2* car   = (float2*)(ws + 256 + NBM * 64);    // NBM*8  =  8192 B
    float2* lblk  = (float2*)(ws + 256 + NBM * 72);    // NBM*8  =  8192 B

    hipMemsetAsync(ws, 0, 16, stream);                 // reset tickets (capturable)
    k_summ<<<NBM, NT, 0, stream>>>(rew, val, msk, blk, car, stats, ctrA);
    k_main<<<NBM, NT, 0, stream>>>(rew, val, msk, act, mu, lv, blp, car, stats, lblk, ctrB, (float*)d_out);
}

// Round 10
// 195.185 us; speedup vs baseline: 1.2300x; 1.0074x over previous
//
#include <hip/hip_runtime.h>
#include <math.h>

#define T_N 2097152
#define NBM 1024               // blocks (4 per CU on 256 CUs)
#define NT 256
#define EPT 8
#define CHUNK (NT * EPT)       // 2048 elements per block
#define GPT (NBM / NT)         // 4 block-summaries per thread in carry/final phases
#define GAMMA_F 0.99f
#define GL_F (0.99f * 0.95f)
#define LOG2PI_F 1.8378770664093453f

// ws layout (slots either rewritten each launch or never read -> poison-safe):
//   ws +      0 : int ctrA, int ctrB     (memset to 0 at launch)
//   ws +     16 : float stats[4]         (mean_a, inv_a, mean_r, inv_r)
//   ws +    256 : float4 blk[NBM*8]      block summaries, 128B-PADDED (one L2 line per record)
//   ws + 131328 : float2 car[NBM]        per-block entering carries (ret, adv)
//   ws + 139520 : float2 lblk[NBM]       per-block loss partials (actor, critic)
//
// Coherence protocol (r3/r4/r5/r8 lessons):
//  - NO __threadfence() (agent fence = per-block L2 writeback-invalidate, 2x slowdown)
//  - publish via sc1 (agent-scope relaxed atomic) stores + s_waitcnt vmcnt(0) + ticket
//  - k_summ tail reads blk with PLAIN CACHED loads: safe because (a) L2s are
//    invalidated at kernel launch, (b) no blk line is read before the last ticket
//    (all sc1 stores drained first), (c) records are 128B-line-exclusive so no
//    partial-line-stale hazard from write-through stores.
//  - cross-KERNEL visibility (car/stats) rides the dispatch boundary (r4-proven)

__device__ __forceinline__ void st_agent(unsigned long long* p, unsigned long long v) {
    __hip_atomic_store(p, v, __ATOMIC_RELAXED, __HIP_MEMORY_SCOPE_AGENT);
}
__device__ __forceinline__ unsigned long long ld_agent(const unsigned long long* p) {
    return __hip_atomic_load(p, __ATOMIC_RELAXED, __HIP_MEMORY_SCOPE_AGENT);
}
__device__ __forceinline__ unsigned long long pk2(float x, float y) {
    union { float2 f; unsigned long long u; } c; c.f = make_float2(x, y); return c.u;
}
__device__ __forceinline__ float2 up2(unsigned long long v) {
    union { float2 f; unsigned long long u; } c; c.u = v; return c.f;
}

// ---------------- affine (A,B) pair for both recurrences ----------------
struct Aff4 { float ar, br, aa, ba; };
__device__ __forceinline__ Aff4 aff_id() { Aff4 o; o.ar = 1.f; o.br = 0.f; o.aa = 1.f; o.ba = 0.f; return o; }
// L earlier in time (applied second in reverse scan): (L o R)(y) = L(R(y))
__device__ __forceinline__ Aff4 aff_compose(const Aff4& L, const Aff4& R) {
    Aff4 o;
    o.ar = L.ar * R.ar;  o.br = fmaf(L.ar, R.br, L.br);
    o.aa = L.aa * R.aa;  o.ba = fmaf(L.aa, R.ba, L.ba);
    return o;
}
__device__ __forceinline__ Aff4 aff_shfl_down(const Aff4& x, int s) {
    Aff4 o;
    o.ar = __shfl_down(x.ar, s, 64); o.br = __shfl_down(x.br, s, 64);
    o.aa = __shfl_down(x.aa, s, 64); o.ba = __shfl_down(x.ba, s, 64);
    return o;
}
__device__ __forceinline__ Aff4 aff_wave_suffix(Aff4 x, int lane) {
#pragma unroll
    for (int s = 1; s < 64; s <<= 1) {
        Aff4 o = aff_shfl_down(x, s);
        if (lane + s < 64) x = aff_compose(x, o);
    }
    return x;
}

// ------------- extended segment: y-map + running sum + running sum-of-squares -------------
// y_out = A*y + B ; Sum(y_t) = P*y + S ; Sum(y_t^2) = U*y^2 + 2*V*y + Q   (y = incoming state)
struct SegF { float A, B, P, S, U, V, Q; };
struct Seg2F { SegF r, a; };

__device__ __forceinline__ SegF segf_compose(const SegF& L, const SegF& R) {
    SegF o;
    o.A = L.A * R.A;
    o.B = fmaf(L.A, R.B, L.B);
    o.P = fmaf(L.P, R.A, R.P);
    o.S = fmaf(L.P, R.B, R.S) + L.S;
    float A2 = R.A * R.A, AB = R.A * R.B, B2 = R.B * R.B;
    o.U = fmaf(L.U, A2, R.U);
    o.V = fmaf(L.U, AB, fmaf(L.V, R.A, R.V));
    o.Q = fmaf(L.U, B2, fmaf(2.f * L.V, R.B, R.Q)) + L.Q;
    return o;
}
__device__ __forceinline__ Seg2F seg2f_compose(const Seg2F& L, const Seg2F& R) {
    Seg2F o; o.r = segf_compose(L.r, R.r); o.a = segf_compose(L.a, R.a); return o;
}
__device__ __forceinline__ SegF segf_shfl_down(const SegF& x, int s) {
    SegF o;
    o.A = __shfl_down(x.A, s, 64); o.B = __shfl_down(x.B, s, 64);
    o.P = __shfl_down(x.P, s, 64); o.S = __shfl_down(x.S, s, 64);
    o.U = __shfl_down(x.U, s, 64); o.V = __shfl_down(x.V, s, 64);
    o.Q = __shfl_down(x.Q, s, 64);
    return o;
}
__device__ __forceinline__ Seg2F seg2f_shfl_down(const Seg2F& x, int s) {
    Seg2F o; o.r = segf_shfl_down(x.r, s); o.a = segf_shfl_down(x.a, s); return o;
}
__device__ __forceinline__ Seg2F seg2f_id() {
    Seg2F o;
    o.r.A = 1.f; o.r.B = 0.f; o.r.P = 0.f; o.r.S = 0.f; o.r.U = 0.f; o.r.V = 0.f; o.r.Q = 0.f;
    o.a = o.r;
    return o;
}

// Affine-only thread transform over EPT contiguous elements (right-to-left).
__device__ __forceinline__ Aff4 thread_transform(const float rr[EPT], const float vv[EPT],
                                                 const float mm[EPT], float vnext) {
    Aff4 x = aff_id();
    float vn = vnext;
#pragma unroll
    for (int j = EPT - 1; j >= 0; --j) {
        float m = mm[j];
        float gm = GAMMA_F * m;
        x.br = fmaf(gm, x.br, rr[j]);  x.ar = gm * x.ar;              // ret: y = gm*y + r
        float delta = fmaf(GAMMA_F * vn, m, rr[j]) - vv[j];
        float gl = GL_F * m;
        x.ba = fmaf(gl, x.ba, delta);  x.aa = gl * x.aa;              // adv: y = gl*y + delta
        vn = vv[j];
    }
    return x;
}

__device__ __forceinline__ void load8(const float* __restrict__ rew,
                                      const float* __restrict__ val,
                                      const int* __restrict__ msk, int g,
                                      float rr[EPT], float vv[EPT], float mm[EPT],
                                      float& vnext) {
    float4 r0 = *(const float4*)(rew + g);
    float4 r1 = *(const float4*)(rew + g + 4);
    float4 v0 = *(const float4*)(val + g);
    float4 v1 = *(const float4*)(val + g + 4);
    int4 m0 = *(const int4*)(msk + g);
    int4 m1 = *(const int4*)(msk + g + 4);
    vnext = (g + EPT < T_N) ? val[g + EPT] : 0.f;
    rr[0]=r0.x; rr[1]=r0.y; rr[2]=r0.z; rr[3]=r0.w; rr[4]=r1.x; rr[5]=r1.y; rr[6]=r1.z; rr[7]=r1.w;
    vv[0]=v0.x; vv[1]=v0.y; vv[2]=v0.z; vv[3]=v0.w; vv[4]=v1.x; vv[5]=v1.y; vv[6]=v1.z; vv[7]=v1.w;
    mm[0]=(float)m0.x; mm[1]=(float)m0.y; mm[2]=(float)m0.z; mm[3]=(float)m0.w;
    mm[4]=(float)m1.x; mm[5]=(float)m1.y; mm[6]=(float)m1.z; mm[7]=(float)m1.w;
}

// blk record layout, 128B padded (idx*8 float4s, quads 0..3 used):
//   q0 = (rA, rB, aA, aB)   q1 = (rP, rS, rU, rV)
//   q2 = (rQ, aP, aS, aU)   q3 = (aV, aQ, pad, pad)
__device__ __forceinline__ Seg2F load_seg_plain(const float4* __restrict__ blk, int idx) {
    float4 q0 = blk[idx * 8 + 0], q1 = blk[idx * 8 + 1];
    float4 q2 = blk[idx * 8 + 2], q3 = blk[idx * 8 + 3];
    Seg2F s;
    s.r.A = q0.x; s.r.B = q0.y; s.a.A = q0.z; s.a.B = q0.w;
    s.r.P = q1.x; s.r.S = q1.y; s.r.U = q1.z; s.r.V = q1.w;
    s.r.Q = q2.x; s.a.P = q2.y; s.a.S = q2.z; s.a.U = q2.w;
    s.a.V = q3.x; s.a.Q = q3.y;
    return s;
}

// loss math for one float4 row
__device__ __forceinline__ void loss_row(float4 a, float4 m, float4 l, float4 bb,
                                         float AD, float RT, float VL,
                                         float mean_a, float inv_a, float mean_r, float inv_r,
                                         float& aacc, float& cacc) {
    float x0 = -0.5f * (a.x - m.x) * (a.x - m.x) * expf(-l.x) - 0.5f * l.x;
    float x1 = -0.5f * (a.y - m.y) * (a.y - m.y) * expf(-l.y) - 0.5f * l.y;
    float x2 = -0.5f * (a.z - m.z) * (a.z - m.z) * expf(-l.z) - 0.5f * l.z;
    float x3 = -0.5f * (a.w - m.w) * (a.w - m.w) * expf(-l.w) - 0.5f * l.w;
    float X = (x0 + x1 + x2 + x3) - (bb.x + bb.y + bb.z + bb.w) - 2.f * LOG2PI_F;
    float ratio = expf(X);
    float rc = fminf(fmaxf(ratio, 0.8f), 1.2f);
    float an = (AD - mean_a) * inv_a;
    aacc += fminf(ratio * an, rc * an);
    float rn = (RT - mean_r) * inv_r;
    float d = VL - rn;
    float adx = fabsf(d);
    cacc += (adx < 1.f) ? 0.5f * d * d : adx - 0.5f;
}

// ============ K1: block summaries (direct accumulation); LAST block: carry scan + stats ============
__global__ __launch_bounds__(NT) void k_summ(const float* __restrict__ rew,
                                             const float* __restrict__ val,
                                             const int* __restrict__ msk,
                                             float4* __restrict__ blk,
                                             float2* __restrict__ car,
                                             float* __restrict__ stats,
                                             int* __restrict__ ctr) {
    int tid = threadIdx.x, lane = tid & 63, wv = tid >> 6;
    int b = blockIdx.x;
    int g = b * CHUNK + tid * EPT;
    float rr[EPT], vv[EPT], mm[EPT], vnext;
    load8(rew, val, msk, g, rr, vv, mm, vnext);

    // direct running-coefficient accumulation (same algebra as elementary-seg
    // composition, ~half the VALU ops): after processing elements j..7, the map
    // y -> out_j is (a,b); accumulate P=Σa_j, S=Σb_j, U=Σa², V=Σab, Q=Σb².
    float arr = 1.f, brr = 0.f, Pr = 0.f, Sr = 0.f, Ur = 0.f, Vr = 0.f, Qr = 0.f;
    float ara = 1.f, bra = 0.f, Pa = 0.f, Sa = 0.f, Ua = 0.f, Va = 0.f, Qa = 0.f;
    float vn = vnext;
#pragma unroll
    for (int j = EPT - 1; j >= 0; --j) {
        float m = mm[j];
        float gm = GAMMA_F * m, gl = GL_F * m;
        arr = gm * arr;  brr = fmaf(gm, brr, rr[j]);
        Pr += arr; Sr += brr;
        Ur = fmaf(arr, arr, Ur); Vr = fmaf(arr, brr, Vr); Qr = fmaf(brr, brr, Qr);
        float delta = fmaf(GAMMA_F * vn, m, rr[j]) - vv[j];
        ara = gl * ara;  bra = fmaf(gl, bra, delta);
        Pa += ara; Sa += bra;
        Ua = fmaf(ara, ara, Ua); Va = fmaf(ara, bra, Va); Qa = fmaf(bra, bra, Qa);
        vn = vv[j];
    }
    Seg2F x;
    x.r.A = arr; x.r.B = brr; x.r.P = Pr; x.r.S = Sr; x.r.U = Ur; x.r.V = Vr; x.r.Q = Qr;
    x.a.A = ara; x.a.B = bra; x.a.P = Pa; x.a.S = Sa; x.a.U = Ua; x.a.V = Va; x.a.Q = Qa;

    // ordered down-reduction: lane 0 ends with composition of lanes [0,64)
#pragma unroll
    for (int s = 1; s < 64; s <<= 1) {
        Seg2F o = seg2f_shfl_down(x, s);
        x = seg2f_compose(x, o);
    }
    __shared__ Seg2F sW[4];
    __shared__ int sDone;
    if (lane == 0) sW[wv] = x;
    __syncthreads();
    if (tid == 0) {
        Seg2F t = sW[3];
        t = seg2f_compose(sW[2], t);
        t = seg2f_compose(sW[1], t);
        t = seg2f_compose(sW[0], t);
        // publish summary: sc1 write-through stores into a private 128B line
        unsigned long long* bp = (unsigned long long*)(blk + (size_t)b * 8);
        st_agent(bp + 0, pk2(t.r.A, t.r.B));
        st_agent(bp + 1, pk2(t.a.A, t.a.B));
        st_agent(bp + 2, pk2(t.r.P, t.r.S));
        st_agent(bp + 3, pk2(t.r.U, t.r.V));
        st_agent(bp + 4, pk2(t.r.Q, t.a.P));
        st_agent(bp + 5, pk2(t.a.S, t.a.U));
        st_agent(bp + 6, pk2(t.a.V, t.a.Q));
        asm volatile("s_waitcnt vmcnt(0)" ::: "memory");   // release: stores at coherence point
        sDone = atomicAdd(ctr, 1);                          // device-coherent ticket
    }
    __syncthreads();
    if (sDone != NBM - 1) return;

    // ---- last block: carry scan over NBM summaries + global stats (CACHED loads) ----
    Seg2F s[GPT];
#pragma unroll
    for (int p = 0; p < GPT; ++p) s[p] = load_seg_plain(blk, tid * GPT + p);
    Seg2F gc = seg2f_id();
#pragma unroll
    for (int p = GPT - 1; p >= 0; --p) gc = seg2f_compose(s[p], gc);
    Seg2F incl = gc;
#pragma unroll
    for (int ss = 1; ss < 64; ss <<= 1) {
        Seg2F o = seg2f_shfl_down(incl, ss);
        if (lane + ss < 64) incl = seg2f_compose(incl, o);
    }
    Seg2F ex = seg2f_shfl_down(incl, 1);
    if (lane == 63) ex = seg2f_id();
    if (lane == 0) sW[wv] = incl;              // safe: phase-1 sW reads done before ticket sync
    __syncthreads();
    Seg2F tail = seg2f_id();
    for (int w = 3; w > wv; --w) tail = seg2f_compose(sW[w], tail);
    Seg2F H = seg2f_compose(ex, tail);         // composition of all summaries after this thread's group
#pragma unroll
    for (int p = GPT - 1; p >= 0; --p) {
        car[tid * GPT + p] = make_float2(H.r.B, H.a.B);   // carry entering block = H(0)
        H = seg2f_compose(s[p], H);
    }
    if (tid == 0) {
        Seg2F tot = seg2f_compose(incl, tail);   // full composition; y_in = 0
        const double Td = (double)T_N;
        double Sa_ = (double)tot.a.S, Qa_ = (double)tot.a.Q;
        double Sr_ = (double)tot.r.S, Qr_ = (double)tot.r.Q;
        double va = (Qa_ - Sa_ * Sa_ / Td) / (Td - 1.0);
        double vr = (Qr_ - Sr_ * Sr_ / Td) / (Td - 1.0);
        stats[0] = (float)(Sa_ / Td);
        stats[1] = (float)(1.0 / (sqrt(va) + 1e-10));
        stats[2] = (float)(Sr_ / Td);
        stats[3] = (float)(1.0 / (sqrt(vr) + 1e-10));
    }
    // car/stats visibility to k_main rides the kernel-boundary implicit flush
}

// ============ K2: scan redo + fused loss (r0-proven body); LAST block: final f64 reduce ============
__global__ __launch_bounds__(NT) void k_main(const float* __restrict__ rew,
                                             const float* __restrict__ val,
                                             const int* __restrict__ msk,
                                             const float4* __restrict__ act,
                                             const float4* __restrict__ mu,
                                             const float4* __restrict__ lv,
                                             const float4* __restrict__ blp,
                                             const float2* __restrict__ car,
                                             const float* __restrict__ stats,
                                             float2* __restrict__ lblk,
                                             int* __restrict__ ctr,
                                             float* __restrict__ out) {
    int tid = threadIdx.x, lane = tid & 63, wv = tid >> 6;
    int b = blockIdx.x;
    int gbase = b * CHUNK;

    // ---- hoisted chunk-A loss loads (rows k=0..3, lane-dense coalesced) ----
    float4 A0[4], M0[4], L0[4], B0[4];
#pragma unroll
    for (int k = 0; k < 4; ++k) {
        int t = gbase + tid + k * NT;
        A0[k] = act[t]; M0[k] = mu[t]; L0[k] = lv[t]; B0[k] = blp[t];
    }
    float mean_a = stats[0], inv_a = stats[1], mean_r = stats[2], inv_r = stats[3];
    float2 c = car[b];

    // ---- scan inputs + phase-1 scan ----
    int g = gbase + tid * EPT;
    float rr[EPT], vv[EPT], mm[EPT], vnext;
    load8(rew, val, msk, g, rr, vv, mm, vnext);
    Aff4 x = thread_transform(rr, vv, mm, vnext);
    Aff4 incl = aff_wave_suffix(x, lane);
    Aff4 ex = aff_shfl_down(incl, 1);
    if (lane == 63) ex = aff_id();
    __shared__ Aff4 sA[4];
    if (lane == 0) sA[wv] = incl;
    __syncthreads();
    Aff4 tail = aff_id();
    for (int w = 3; w > wv; --w) tail = aff_compose(sA[w], tail);
    ex = aff_compose(ex, tail);
    float yr = fmaf(ex.ar, c.x, ex.br);
    float ya = fmaf(ex.aa, c.y, ex.ba);
    float retj[EPT], advj[EPT];
    float vn = vnext;
#pragma unroll
    for (int j = EPT - 1; j >= 0; --j) {
        float m = mm[j];
        float gm = GAMMA_F * m;
        yr = fmaf(gm, yr, rr[j]);  retj[j] = yr;
        float delta = fmaf(GAMMA_F * vn, m, rr[j]) - vv[j];
        ya = fmaf(GL_F * m, ya, delta);  advj[j] = ya;
        vn = vv[j];
    }
    // ---- LDS bridge: scan layout -> lane-dense ----
    __shared__ float sAdv[CHUNK], sRet[CHUNK], sVal[CHUNK];
    *(float4*)(sAdv + tid * EPT)     = make_float4(advj[0], advj[1], advj[2], advj[3]);
    *(float4*)(sAdv + tid * EPT + 4) = make_float4(advj[4], advj[5], advj[6], advj[7]);
    *(float4*)(sRet + tid * EPT)     = make_float4(retj[0], retj[1], retj[2], retj[3]);
    *(float4*)(sRet + tid * EPT + 4) = make_float4(retj[4], retj[5], retj[6], retj[7]);
    *(float4*)(sVal + tid * EPT)     = make_float4(vv[0], vv[1], vv[2], vv[3]);
    *(float4*)(sVal + tid * EPT + 4) = make_float4(vv[4], vv[5], vv[6], vv[7]);
    __syncthreads();

    // ---- chunk-B loss loads (rows k=4..7) issued before chunk-A math ----
    float4 A1[4], M1[4], L1[4], B1[4];
#pragma unroll
    for (int k = 0; k < 4; ++k) {
        int t = gbase + tid + (k + 4) * NT;
        A1[k] = act[t]; M1[k] = mu[t]; L1[k] = lv[t]; B1[k] = blp[t];
    }

    float aacc = 0.f, cacc = 0.f;
#pragma unroll
    for (int k = 0; k < 4; ++k) {
        int r = tid + k * NT;
        loss_row(A0[k], M0[k], L0[k], B0[k], sAdv[r], sRet[r], sVal[r],
                 mean_a, inv_a, mean_r, inv_r, aacc, cacc);
    }
#pragma unroll
    for (int k = 0; k < 4; ++k) {
        int r = tid + (k + 4) * NT;
        loss_row(A1[k], M1[k], L1[k], B1[k], sAdv[r], sRet[r], sVal[r],
                 mean_a, inv_a, mean_r, inv_r, aacc, cacc);
    }
#pragma unroll
    for (int s = 32; s > 0; s >>= 1) {
        aacc += __shfl_xor(aacc, s, 64);
        cacc += __shfl_xor(cacc, s, 64);
    }
    __shared__ float2 sL[4];
    __shared__ int sDone;
    if (lane == 0) sL[wv] = make_float2(aacc, cacc);
    __syncthreads();
    if (tid == 0) {
        st_agent((unsigned long long*)(lblk + b),
                 pk2(sL[0].x + sL[1].x + sL[2].x + sL[3].x,
                     sL[0].y + sL[1].y + sL[2].y + sL[3].y));
        asm volatile("s_waitcnt vmcnt(0)" ::: "memory");
        sDone = atomicAdd(ctr, 1);
    }
    __syncthreads();
    if (sDone != NBM - 1) return;

    // ---- last block: final reduce in double (sc1 reads; only 4 x 8B per thread) ----
    double ac = 0, cr = 0;
#pragma unroll
    for (int p = 0; p < NBM / NT; ++p) {
        float2 v2 = up2(ld_agent((const unsigned long long*)(lblk + tid + p * NT)));
        ac += v2.x; cr += v2.y;
    }
#pragma unroll
    for (int s = 32; s > 0; s >>= 1) {
        ac += __shfl_xor(ac, s, 64);
        cr += __shfl_xor(cr, s, 64);
    }
    __shared__ double sD[4][2];
    if (lane == 0) { sD[wv][0] = ac; sD[wv][1] = cr; }
    __syncthreads();
    if (tid == 0) {
        ac = sD[0][0] + sD[1][0] + sD[2][0] + sD[3][0];
        cr = sD[0][1] + sD[1][1] + sD[2][1] + sD[3][1];
        out[0] = (float)((-ac + cr) / (double)T_N);
    }
}

extern "C" void kernel_launch(void* const* d_in, const int* in_sizes, int n_in,
                              void* d_out, int out_size, void* d_ws, size_t ws_size,
                              hipStream_t stream) {
    const float* rew = (const float*)d_in[0];
    const float* val = (const float*)d_in[1];
    const float4* blp = (const float4*)d_in[2];
    const float4* act = (const float4*)d_in[3];
    const float4* mu  = (const float4*)d_in[4];
    const float4* lv  = (const float4*)d_in[5];
    const int*   msk = (const int*)d_in[6];

    char* ws = (char*)d_ws;
    int*    ctrA  = (int*)ws;                           // 4 B
    int*    ctrB  = (int*)(ws + 4);                     // 4 B
    float*  stats = (float*)(ws + 16);                  // 16 B
    float4* blk   = (float4*)(ws + 256);                // NBM*128 = 131072 B (padded records)
    float2* car   = (float2*)(ws + 256 + NBM * 128);    // NBM*8 = 8192 B
    float2* lblk  = (float2*)(ws + 256 + NBM * 136);    // NBM*8 = 8192 B

    hipMemsetAsync(ws, 0, 16, stream);                  // reset tickets (capturable)
    k_summ<<<NBM, NT, 0, stream>>>(rew, val, msk, blk, car, stats, ctrA);
    k_main<<<NBM, NT, 0, stream>>>(rew, val, msk, act, mu, lv, blp, car, stats, lblk, ctrB, (float*)d_out);
}